// Round 3
// baseline (1489.042 us; speedup 1.0000x reference)
//
#include <hip/hip_runtime.h>
#include <hip/hip_fp16.h>

typedef _Float16 f16;
typedef _Float16 f16x4 __attribute__((ext_vector_type(4)));
typedef _Float16 f16x8 __attribute__((ext_vector_type(8)));
typedef float f32x4 __attribute__((ext_vector_type(4)));

#define SS 2048
#define BB 2
#define HH 16
#define DHH 64
#define DMM 1024

typedef const __attribute__((address_space(1))) void gvoid_t;
typedef __attribute__((address_space(3))) void lvoid_t;
#define ASYNC_COPY16(g, l) __builtin_amdgcn_global_load_lds((gvoid_t*)(g), (lvoid_t*)(l), 16, 0, 0)

// ---------------- fp32 -> fp16 convert (vectorized) ----------------
__global__ void cvt_f16_kernel(const float* __restrict__ s, f16* __restrict__ d, int n4) {
    int i = blockIdx.x * 256 + threadIdx.x;
    if (i >= n4) return;
    float4 v = ((const float4*)s)[i];
    f16x4 o = { (f16)v.x, (f16)v.y, (f16)v.z, (f16)v.w };
    ((f16x4*)d)[i] = o;
}

// ---------------- MLP layer 0: h0[d][j] = silu(d * pw0[j] + pb0[j]), d in [0,2048) ----------------
__global__ void mlp0_kernel(const float* __restrict__ pw0, const float* __restrict__ pb0,
                            f16* __restrict__ h0) {
    int i = blockIdx.x * 256 + threadIdx.x;     // 2048*1024 total
    int d = i >> 10, j = i & 1023;
    float pre = fmaf((float)d, pw0[j], pb0[j]);
    float v = pre / (1.f + __expf(-pre));
    h0[i] = (f16)v;
}

// ---------------- MLP layer 3 (fp32): tbl[d][h] = sum_k h2[d][k]*pw3[h][k] + pb3[h] ----------------
__global__ void mlp3_kernel(const f16* __restrict__ h2, const float* __restrict__ pw3,
                            const float* __restrict__ pb3, float* __restrict__ tbl) {
    int d = blockIdx.x;          // 2048 blocks
    int lane = threadIdx.x;      // 64 threads
    float acc[16];
#pragma unroll
    for (int h = 0; h < 16; ++h) acc[h] = 0.f;
#pragma unroll
    for (int kk = 0; kk < 16; ++kk) {
        int k = kk * 64 + lane;
        float hv = (float)h2[(size_t)d * 1024 + k];
#pragma unroll
        for (int h = 0; h < 16; ++h) acc[h] = fmaf(hv, pw3[h * 1024 + k], acc[h]);
    }
#pragma unroll
    for (int h = 0; h < 16; ++h) {
        acc[h] += __shfl_xor(acc[h], 1);
        acc[h] += __shfl_xor(acc[h], 2);
        acc[h] += __shfl_xor(acc[h], 4);
        acc[h] += __shfl_xor(acc[h], 8);
        acc[h] += __shfl_xor(acc[h], 16);
        acc[h] += __shfl_xor(acc[h], 32);
    }
    if (lane == 0) {
#pragma unroll
        for (int h = 0; h < 16; ++h) tbl[d * 16 + h] = acc[h] + pb3[h];
    }
}

// ---------------- generic fp16 GEMM-BT: C[M,N] = A[M,K] @ B[N,K]^T + bias, opt SiLU ----------------
// 128x128 tile, BK=64, 4 waves (2x2), global_load_lds staging with XOR-swizzled LDS.
template<int ACT, int OF16>
__global__ __launch_bounds__(256)
void gemm_bt(const f16* __restrict__ A, const f16* __restrict__ Bm,
             const float* __restrict__ bias, void* __restrict__ Cout,
             int M, int N, int K) {
    __shared__ __attribute__((aligned(16))) f16 Ash[128 * 64];
    __shared__ __attribute__((aligned(16))) f16 Bsh[128 * 64];
    const int tm = blockIdx.x * 128, tn = blockIdx.y * 128;
    const int tid = threadIdx.x, wid = tid >> 6, lane = tid & 63;
    const int g = lane >> 4, r = lane & 15;
    const int wr = wid >> 1, wc = wid & 1;
    const int srow = wid * 8 + (lane >> 3);          // row within 32-row staging group
    const int schunk = (lane & 7) ^ (srow & 7);      // pre-swizzled source chunk (16B units)
    f32x4 acc[4][4] = {};
    for (int k0 = 0; k0 < K; k0 += 64) {
        __syncthreads();
#pragma unroll
        for (int i = 0; i < 4; ++i) {
            int row = i * 32 + srow;
            ASYNC_COPY16(A + (size_t)(tm + row) * K + k0 + schunk * 8,
                         (char*)Ash + (i * 32 + wid * 8) * 128);
            ASYNC_COPY16(Bm + (size_t)(tn + row) * K + k0 + schunk * 8,
                         (char*)Bsh + (i * 32 + wid * 8) * 128);
        }
        __syncthreads();
#pragma unroll
        for (int ks = 0; ks < 2; ++ks) {
            f16x8 af[4], bf[4];
#pragma unroll
            for (int m = 0; m < 4; ++m) {
                int row = wr * 64 + m * 16 + r;
                af[m] = *(const f16x8*)((const char*)Ash + row * 128 +
                                        ((ks * 64 + g * 16) ^ ((row & 7) << 4)));
            }
#pragma unroll
            for (int n = 0; n < 4; ++n) {
                int row = wc * 64 + n * 16 + r;
                bf[n] = *(const f16x8*)((const char*)Bsh + row * 128 +
                                        ((ks * 64 + g * 16) ^ ((row & 7) << 4)));
            }
#pragma unroll
            for (int m = 0; m < 4; ++m)
#pragma unroll
                for (int n = 0; n < 4; ++n)
                    acc[m][n] = __builtin_amdgcn_mfma_f32_16x16x32_f16(af[m], bf[n], acc[m][n], 0, 0, 0);
        }
    }
#pragma unroll
    for (int n = 0; n < 4; ++n) {
        int col = tn + wc * 64 + n * 16 + r;
        float bv = bias[col];
#pragma unroll
        for (int m = 0; m < 4; ++m) {
            int row0 = tm + wr * 64 + m * 16 + g * 4;
#pragma unroll
            for (int j = 0; j < 4; ++j) {
                float v = acc[m][n][j] + bv;
                if (ACT) v = v / (1.f + __expf(-v));
                if (OF16) ((f16*)Cout)[(size_t)(row0 + j) * N + col] = (f16)v;
                else      ((float*)Cout)[(size_t)(row0 + j) * N + col] = v;
            }
        }
    }
}

// ---------------- V transpose: (b,s,h,d) -> (b*h, d, s) ----------------
__global__ void transpose_v_kernel(const f16* __restrict__ v, f16* __restrict__ vt) {
    __shared__ ushort t[64][65];
    int s0 = blockIdx.x * 64;
    int bh = blockIdx.y;            // b*16 + h
    int b = bh >> 4, h = bh & 15;
    int tid = threadIdx.x;          // 256
#pragma unroll
    for (int i = 0; i < 16; ++i) {
        int idx = tid + 256 * i;
        int sl = idx >> 6, dl = idx & 63;
        t[sl][dl] = ((const ushort*)v)[((size_t)(b * SS + s0 + sl) * HH + h) * DHH + dl];
    }
    __syncthreads();
#pragma unroll
    for (int i = 0; i < 16; ++i) {
        int idx = tid + 256 * i;
        int dl = idx >> 6, sl = idx & 63;
        ((ushort*)vt)[((size_t)bh * DHH + dl) * SS + s0 + sl] = t[sl][dl];
    }
}

// ---------------- fused attention: QK^T + bias + causal mask + softmax + attn-write + PV ----------------
// grid (S/64, B*H), 4 waves; wave w owns q rows [qt*64+16w, +16). Two-pass online softmax
// (pass A: m,l stats; pass B: write attn fp32 + accumulate ctx via LDS-transposed P).
__global__ __launch_bounds__(256)
void attn_fused(const f16* __restrict__ q16, const f16* __restrict__ k16,
                const f16* __restrict__ vt16, const float* __restrict__ tbl,
                float* __restrict__ attn_out, f16* __restrict__ ctx16) {
    __shared__ __attribute__((aligned(16))) f16 p_lds[4][16 * 64];
    const int qt = blockIdx.x, bh = blockIdx.y;
    const int b = bh >> 4, h = bh & 15;
    const int tid = threadIdx.x, wid = tid >> 6, lane = tid & 63;
    const int g = lane >> 4, r = lane & 15;
    const int qw = qt * 64 + wid * 16;

    f16x8 qf0, qf1;
    {
        const f16* qb = q16 + ((size_t)((b * SS + qw + r) * HH + h)) * DHH;
        qf0 = *(const f16x8*)(qb + g * 8);
        qf1 = *(const f16x8*)(qb + 32 + g * 8);
    }
    const f16* kb_base = k16 + ((size_t)(b * SS) * HH + h) * DHH;

    auto compute_sc = [&](int kt, float (&sc)[4][4]) {
        int k0 = kt * 64;
#pragma unroll
        for (int cf = 0; cf < 4; ++cf) {
            const f16* kr = kb_base + (size_t)(k0 + cf * 16 + r) * HH * DHH;
            f16x8 b0 = *(const f16x8*)(kr + g * 8);
            f16x8 b1 = *(const f16x8*)(kr + 32 + g * 8);
            f32x4 a = {0.f, 0.f, 0.f, 0.f};
            a = __builtin_amdgcn_mfma_f32_16x16x32_f16(qf0, b0, a, 0, 0, 0);
            a = __builtin_amdgcn_mfma_f32_16x16x32_f16(qf1, b1, a, 0, 0, 0);
#pragma unroll
            for (int j = 0; j < 4; ++j) {
                int qa = qw + g * 4 + j;
                int ka = k0 + cf * 16 + r;
                int dd = qa - ka;
                float bia = tbl[(dd < 0 ? 0 : dd) * 16 + h];   // clamp keeps load in-bounds
                sc[cf][j] = (dd >= 0) ? fmaf(a[j], 0.125f, bia) : -1e9f;
            }
        }
    };

    float m[4], l[4];
#pragma unroll
    for (int j = 0; j < 4; ++j) { m[j] = -1e30f; l[j] = 0.f; }

    // ---- pass A: online (m, l) ----
    for (int kt = 0; kt <= qt; ++kt) {
        float sc[4][4];
        compute_sc(kt, sc);
#pragma unroll
        for (int j = 0; j < 4; ++j) {
            float mx = fmaxf(fmaxf(sc[0][j], sc[1][j]), fmaxf(sc[2][j], sc[3][j]));
            mx = fmaxf(mx, __shfl_xor(mx, 1));
            mx = fmaxf(mx, __shfl_xor(mx, 2));
            mx = fmaxf(mx, __shfl_xor(mx, 4));
            mx = fmaxf(mx, __shfl_xor(mx, 8));
            float mn = fmaxf(m[j], mx);
            float sum = __expf(sc[0][j] - mn) + __expf(sc[1][j] - mn) +
                        __expf(sc[2][j] - mn) + __expf(sc[3][j] - mn);
            sum += __shfl_xor(sum, 1);
            sum += __shfl_xor(sum, 2);
            sum += __shfl_xor(sum, 4);
            sum += __shfl_xor(sum, 8);
            l[j] = l[j] * __expf(m[j] - mn) + sum;
            m[j] = mn;
        }
    }
    float rinv[4];
#pragma unroll
    for (int j = 0; j < 4; ++j) rinv[j] = 1.f / l[j];

    // ---- pass B: write attn, accumulate ctx ----
    f32x4 acc[4] = {};
    float* arow = attn_out + (size_t)bh * SS * SS;
    const f16* vb = vt16 + (size_t)bh * DHH * SS;
    for (int kt = 0; kt < SS / 64; ++kt) {
        int k0 = kt * 64;
        if (kt <= qt) {
            float sc[4][4];
            compute_sc(kt, sc);
#pragma unroll
            for (int cf = 0; cf < 4; ++cf) {
#pragma unroll
                for (int j = 0; j < 4; ++j) {
                    int row = g * 4 + j;
                    int qa = qw + row;
                    int ka = k0 + cf * 16 + r;
                    float p = __expf(sc[cf][j] - m[j]) * rinv[j];
                    arow[(size_t)qa * SS + ka] = p;       // masked -> exp(-1e9-m)/l == 0
                    p_lds[wid][row * 64 + ((cf * 16 + r) ^ ((row & 7) << 3))] = (f16)p;
                }
            }
#pragma unroll
            for (int ks = 0; ks < 2; ++ks) {
                f16x8 pf = *(const f16x8*)&p_lds[wid][r * 64 + ((ks * 32 + g * 8) ^ ((r & 7) << 3))];
#pragma unroll
                for (int df = 0; df < 4; ++df) {
                    f16x8 vf = *(const f16x8*)(vb + (size_t)(df * 16 + r) * SS + k0 + ks * 32 + g * 8);
                    acc[df] = __builtin_amdgcn_mfma_f32_16x16x32_f16(pf, vf, acc[df], 0, 0, 0);
                }
            }
        } else {
#pragma unroll
            for (int cf = 0; cf < 4; ++cf)
#pragma unroll
                for (int j = 0; j < 4; ++j) {
                    int qa = qw + g * 4 + j;
                    arow[(size_t)qa * SS + k0 + cf * 16 + r] = 0.f;
                }
        }
    }
#pragma unroll
    for (int df = 0; df < 4; ++df)
#pragma unroll
        for (int j = 0; j < 4; ++j) {
            int qa = qw + g * 4 + j;
            ctx16[((size_t)(b * SS + qa) * HH + h) * DHH + df * 16 + r] = (f16)acc[df][j];
        }
}

// ---------------- launch ----------------
extern "C" void kernel_launch(void* const* d_in, const int* in_sizes, int n_in,
                              void* d_out, int out_size, void* d_ws, size_t ws_size,
                              hipStream_t stream) {
    const float* query = (const float*)d_in[0];
    const float* key_  = (const float*)d_in[1];
    const float* value = (const float*)d_in[2];
    const float* wq  = (const float*)d_in[3];
    const float* bq  = (const float*)d_in[4];
    const float* wk  = (const float*)d_in[5];
    const float* bk  = (const float*)d_in[6];
    const float* wv  = (const float*)d_in[7];
    const float* bv  = (const float*)d_in[8];
    const float* wo  = (const float*)d_in[9];
    const float* bo  = (const float*)d_in[10];
    const float* pw0 = (const float*)d_in[11];
    const float* pb0 = (const float*)d_in[12];
    const float* pw1 = (const float*)d_in[13];
    const float* pb1 = (const float*)d_in[14];
    const float* pw2 = (const float*)d_in[15];
    const float* pb2 = (const float*)d_in[16];
    const float* pw3 = (const float*)d_in[17];
    const float* pb3 = (const float*)d_in[18];

    float* out_f  = (float*)d_out;
    float* attn_f = out_f + (size_t)BB * SS * DMM;       // 4,194,304 floats in

    // true scratch (alive during attention / out-proj) in d_ws: 34.2 MB
    const size_t NEED = (size_t)36 * 1024 * 1024;
    if (ws_size < NEED) return;
    char* ws = (char*)d_ws;
    f16*   q16   = (f16*)(ws);                        // 8 MB
    f16*   k16   = (f16*)(ws + ((size_t)8  << 20));   // 8 MB
    f16*   vt16  = (f16*)(ws + ((size_t)16 << 20));   // 8 MB
    f16*   ctx16 = (f16*)(ws + ((size_t)24 << 20));   // 8 MB
    f16*   wo16  = (f16*)(ws + ((size_t)32 << 20));   // 2 MB
    float* tbl   = (float*)(ws + ((size_t)34 << 20)); // 128 KB

    // early-phase scratch inside the attn output region (dead before attn_fused runs; 536 MB avail)
    char* dsc = (char*)attn_f;
    f16* xq    = (f16*)(dsc);
    f16* xk    = (f16*)(dsc + ((size_t)8  << 20));
    f16* xv    = (f16*)(dsc + ((size_t)16 << 20));
    f16* v16   = (f16*)(dsc + ((size_t)24 << 20));
    f16* wq16  = (f16*)(dsc + ((size_t)32 << 20));
    f16* wk16  = (f16*)(dsc + ((size_t)34 << 20));
    f16* wv16  = (f16*)(dsc + ((size_t)36 << 20));
    f16* pw1h  = (f16*)(dsc + ((size_t)38 << 20));
    f16* pw2h  = (f16*)(dsc + ((size_t)40 << 20));
    f16* h0    = (f16*)(dsc + ((size_t)42 << 20));   // 2048x1024 = 4MB
    f16* h1    = (f16*)(dsc + ((size_t)46 << 20));

    // converts
    cvt_f16_kernel<<<4096, 256, 0, stream>>>(query, xq, (BB * SS * DMM) / 4);
    cvt_f16_kernel<<<4096, 256, 0, stream>>>(key_,  xk, (BB * SS * DMM) / 4);
    cvt_f16_kernel<<<4096, 256, 0, stream>>>(value, xv, (BB * SS * DMM) / 4);
    cvt_f16_kernel<<<1024, 256, 0, stream>>>(wq,  wq16, (DMM * DMM) / 4);
    cvt_f16_kernel<<<1024, 256, 0, stream>>>(wk,  wk16, (DMM * DMM) / 4);
    cvt_f16_kernel<<<1024, 256, 0, stream>>>(wv,  wv16, (DMM * DMM) / 4);
    cvt_f16_kernel<<<1024, 256, 0, stream>>>(wo,  wo16, (DMM * DMM) / 4);
    cvt_f16_kernel<<<1024, 256, 0, stream>>>(pw1, pw1h, (DMM * DMM) / 4);
    cvt_f16_kernel<<<1024, 256, 0, stream>>>(pw2, pw2h, (DMM * DMM) / 4);

    // rel-pos-bias MLP (only d = q-k in [0,2048) is reachable under the causal mask)
    mlp0_kernel<<<8192, 256, 0, stream>>>(pw0, pb0, h0);
    gemm_bt<1, 1><<<dim3(16, 8), 256, 0, stream>>>(h0, pw1h, pb1, h1, 2048, 1024, 1024);
    gemm_bt<1, 1><<<dim3(16, 8), 256, 0, stream>>>(h1, pw2h, pb2, h0, 2048, 1024, 1024);
    mlp3_kernel<<<2048, 64, 0, stream>>>(h0, pw3, pb3, tbl);

    // QKV projections
    gemm_bt<0, 1><<<dim3(32, 8), 256, 0, stream>>>(xq, wq16, bq, q16, 4096, 1024, 1024);
    gemm_bt<0, 1><<<dim3(32, 8), 256, 0, stream>>>(xk, wk16, bk, k16, 4096, 1024, 1024);
    gemm_bt<0, 1><<<dim3(32, 8), 256, 0, stream>>>(xv, wv16, bv, v16, 4096, 1024, 1024);
    transpose_v_kernel<<<dim3(32, 32), 256, 0, stream>>>(v16, vt16);

    // fused attention: writes full attn (B,H,S,S) fp32 + ctx16
    attn_fused<<<dim3(32, 32), 256, 0, stream>>>(q16, k16, vt16, tbl, attn_f, ctx16);

    // output projection
    gemm_bt<0, 0><<<dim3(32, 8), 256, 0, stream>>>(ctx16, wo16, bo, out_f, 4096, 1024, 1024);
}